// Round 1
// baseline (499.207 us; speedup 1.0000x reference)
//
#include <hip/hip_runtime.h>

#define P_DIM 1024
#define H_DIM 256
#define L_DIM 16384
#define DT 0.001f
#define BM 64
#define BN 128
#define KC 16
#define NTHREADS 256

__device__ __forceinline__ float2 cmul(float2 a, float2 b) {
    return make_float2(a.x * b.x - a.y * b.y, a.x * b.y + a.y * b.x);
}

// kernel[h,l] = sum_p W[h,p] * V[p,l]
//   W[h,p] = C[h,p] * scale[p] * B[p,h],  scale[p] = (exp(Ac*DT)-1)/Ac
//   V[p,l] = exp(Ar*DT*l) * (cos(Ai*DT*l), sin(Ai*DT*l))
// Block computes a 64(h) x 128(l) tile; thread computes 8x4 complex outputs.
__global__ __launch_bounds__(NTHREADS)
void vand_kernel(const float* __restrict__ Ag,
                 const float* __restrict__ Bg,
                 const float* __restrict__ Cg,
                 float* __restrict__ out) {
    __shared__ float4 prep[KC];                              // {dA, rev/step, scale_r, scale_i}
    __shared__ float Ct[KC][2 * BM + 2];                     // transposed C tile (padded)
    __shared__ __attribute__((aligned(16))) float Wt[KC][2 * BM];  // W tile, interleaved re/im
    __shared__ __attribute__((aligned(16))) float Vr[KC][BN];
    __shared__ __attribute__((aligned(16))) float Vi[KC][BN];

    const int tid  = threadIdx.x;
    const int lb   = blockIdx.x * BN;
    const int hb   = blockIdx.y * BM;
    const int rowg = tid >> 5;   // 0..7  -> rows rowg*8..+7
    const int colg = tid & 31;   // 0..31 -> cols colg*4..+3

    const float2* C2 = (const float2*)Cg;
    const float2* B2 = (const float2*)Bg;

    float accR[8][4], accI[8][4];
    #pragma unroll
    for (int m = 0; m < 8; ++m)
        #pragma unroll
        for (int n = 0; n < 4; ++n) { accR[m][n] = 0.f; accI[m][n] = 0.f; }

    // V-gen mapping: thread handles p=vp, l = vl0..vl0+7
    const int vp  = tid >> 4;
    const int vl0 = (tid & 15) * 8;

    for (int k0 = 0; k0 < P_DIM; k0 += KC) {
        // ---- global loads to regs (both coalesced) ----
        float2 breg[4], creg[4];
        #pragma unroll
        for (int r = 0; r < 4; ++r) {
            int e  = r * NTHREADS + tid;
            int pb = e >> 6, hbl = e & 63;            // B: (p-major, h-minor)
            breg[r] = B2[(size_t)(k0 + pb) * H_DIM + (hb + hbl)];
            int hc = e >> 4, pc = e & 15;             // C: (h-major, p-minor)
            creg[r] = C2[(size_t)(hb + hc) * P_DIM + (k0 + pc)];
        }
        __syncthreads();  // previous MAC loop done reading Wt/Vr/Vi & prep

        // ---- per-chunk prep (16 threads) ----
        if (tid < KC) {
            int p = k0 + tid;
            float Arv = Ag[2 * p], Aiv = Ag[2 * p + 1];
            float th = Aiv * DT;
            float er = __expf(Arv * DT);
            float s, c;
            __sincosf(th, &s, &c);
            float nr  = er * c - 1.0f;
            float ni  = er * s;
            float inv = 1.0f / (Arv * Arv + Aiv * Aiv);
            prep[tid] = make_float4(Arv * DT,
                                    th * 0.15915494309189535f,   // revolutions per step
                                    (nr * Arv + ni * Aiv) * inv,
                                    (ni * Arv - nr * Aiv) * inv);
        }
        // ---- C tile -> LDS, transposed ----
        #pragma unroll
        for (int r = 0; r < 4; ++r) {
            int e  = r * NTHREADS + tid;
            int hc = e >> 4, pc = e & 15;
            Ct[pc][2 * hc]     = creg[r].x;
            Ct[pc][2 * hc + 1] = creg[r].y;
        }
        __syncthreads();  // prep + Ct visible

        // ---- V tile gen (exp + sincos, phase kept in revolutions: max 8.2 rev) ----
        {
            float4 pr = prep[vp];
            float dA = pr.x, t2p = pr.y;
            #pragma unroll
            for (int j = 0; j < 8; ++j) {
                float fl  = (float)(lb + vl0 + j);
                float mag = __expf(dA * fl);
                float x   = t2p * fl;
                x -= rintf(x);
                float s, c;
                __sincosf(x * 6.283185307179586f, &s, &c);
                Vr[vp][vl0 + j] = mag * c;
                Vi[vp][vl0 + j] = mag * s;
            }
        }
        // ---- W tile gen: W[p][h] = C[h][p]*B[p][h]*scale[p] ----
        #pragma unroll
        for (int r = 0; r < 4; ++r) {
            int e  = r * NTHREADS + tid;
            int pb = e >> 6, hbl = e & 63;
            float4 pr = prep[pb];
            float2 cv = make_float2(Ct[pb][2 * hbl], Ct[pb][2 * hbl + 1]);
            float2 w  = cmul(cmul(cv, breg[r]), make_float2(pr.z, pr.w));
            Wt[pb][2 * hbl]     = w.x;
            Wt[pb][2 * hbl + 1] = w.y;
        }
        __syncthreads();  // Wt/Vr/Vi ready

        // ---- MAC loop: 128 FMA per p-step per thread vs 6 ds_read_b128 ----
        #pragma unroll 4
        for (int pi = 0; pi < KC; ++pi) {
            float wf[16];
            const float* wrow = &Wt[pi][rowg * 16];
            #pragma unroll
            for (int k = 0; k < 4; ++k)
                *(float4*)&wf[4 * k] = *(const float4*)(wrow + 4 * k);
            float4 vr4 = *(const float4*)&Vr[pi][colg * 4];
            float4 vi4 = *(const float4*)&Vi[pi][colg * 4];
            float vr[4] = {vr4.x, vr4.y, vr4.z, vr4.w};
            float vi[4] = {vi4.x, vi4.y, vi4.z, vi4.w};
            #pragma unroll
            for (int m = 0; m < 8; ++m) {
                float wr = wf[2 * m], wi = wf[2 * m + 1];
                #pragma unroll
                for (int n = 0; n < 4; ++n) {
                    accR[m][n] = fmaf(wr,  vr[n], accR[m][n]);
                    accR[m][n] = fmaf(-wi, vi[n], accR[m][n]);
                    accI[m][n] = fmaf(wr,  vi[n], accI[m][n]);
                    accI[m][n] = fmaf(wi,  vr[n], accI[m][n]);
                }
            }
        }
    }

    // ---- epilogue: out (H, L, 2), 2x float4 per row ----
    #pragma unroll
    for (int m = 0; m < 8; ++m) {
        int h = hb + rowg * 8 + m;
        size_t base = ((size_t)h * L_DIM + (lb + colg * 4)) * 2;
        float4 o0 = make_float4(accR[m][0], accI[m][0], accR[m][1], accI[m][1]);
        float4 o1 = make_float4(accR[m][2], accI[m][2], accR[m][3], accI[m][3]);
        *(float4*)&out[base]     = o0;
        *(float4*)&out[base + 4] = o1;
    }
}

extern "C" void kernel_launch(void* const* d_in, const int* in_sizes, int n_in,
                              void* d_out, int out_size, void* d_ws, size_t ws_size,
                              hipStream_t stream) {
    const float* A = (const float*)d_in[0];   // (P, 2)
    const float* B = (const float*)d_in[1];   // (P, H, 2)
    const float* C = (const float*)d_in[2];   // (H, P, 2)
    float* out = (float*)d_out;               // (H, L, 2)

    dim3 grid(L_DIM / BN, H_DIM / BM);        // (128, 4)
    dim3 block(NTHREADS);
    vand_kernel<<<grid, block, 0, stream>>>(A, B, C, out);
}

// Round 2
// 115.554 us; speedup vs baseline: 4.3201x; 4.3201x over previous
//
#include <hip/hip_runtime.h>
#include <hip/hip_fp16.h>

#define P_DIM 1024
#define H_DIM 256
#define L_DIM 16384
#define DT 0.001f
#define TWOPI 6.283185307179586f
#define WSCALE 4096.0f
#define INV_WSCALE (1.0f / 4096.0f)

// GEMM view: out[m][n] = sum_k A[m][k] * Bv[k][n]
//   m = h (256), k = 2p+s (2048), n = 2l+t (32768) -> out (H, L, 2) flat.
//   A[h][2p]   = Wr[h,p]*4096,  A[h][2p+1] = Wi[h,p]*4096   (fp16, in d_ws)
//   Bv[2p][2l] = Vr, Bv[2p][2l+1] = Vi, Bv[2p+1][2l] = -Vi, Bv[2p+1][2l+1] = Vr
#define BM 128
#define BN 128
#define BK 64
#define NTHREADS 256

typedef _Float16 f16x8 __attribute__((ext_vector_type(8)));
typedef float f32x4 __attribute__((ext_vector_type(4)));

#define GPTR(p) (const __attribute__((address_space(1))) unsigned*)(p)
#define LPTR(p) (__attribute__((address_space(3))) unsigned*)(p)

union H2U { __half2 h; unsigned u; };

// ---------- prep: W_hat[h][k] fp16, scaled by 4096 ----------
__global__ __launch_bounds__(256)
void prep_kernel(const float* __restrict__ Ag, const float* __restrict__ Bg,
                 const float* __restrict__ Cg, __half* __restrict__ W2) {
    int gid = blockIdx.x * 256 + threadIdx.x;      // 262144 total
    int h = gid >> 10, p = gid & 1023;
    float2 a = ((const float2*)Ag)[p];
    float er = __expf(a.x * DT);
    float s, c;
    __sincosf(a.y * DT, &s, &c);
    float nr = er * c - 1.0f, ni = er * s;
    float inv = 1.0f / (a.x * a.x + a.y * a.y);
    float sr = (nr * a.x + ni * a.y) * inv;
    float si = (ni * a.x - nr * a.y) * inv;
    float2 b = ((const float2*)Bg)[p * H_DIM + h];
    float2 cc = ((const float2*)Cg)[h * P_DIM + p];
    float tr = cc.x * sr - cc.y * si, ti = cc.x * si + cc.y * sr;
    float wr = (tr * b.x - ti * b.y) * WSCALE;
    float wi = (tr * b.y + ti * b.x) * WSCALE;
    ((__half2*)W2)[h * P_DIM + p] = __float22half2_rn(make_float2(wr, wi));
}

// ---------- main fused GEMM + V generation ----------
// LDS A/B tiles: [row][64] f16, XOR swizzle: element k of row r lives at
// slot ((k>>3) ^ (r&7))*8 + (k&7)  -> conflict-free b128 MFMA reads, 16B rows.
__global__ __launch_bounds__(NTHREADS)
void vand_mfma_kernel(const float* __restrict__ Ag,
                      const _Float16* __restrict__ W2,
                      float* __restrict__ out) {
    __shared__ __attribute__((aligned(16))) _Float16 As[BM * BK];
    __shared__ __attribute__((aligned(16))) _Float16 Bs[BN * BK];
    __shared__ __attribute__((aligned(16))) float2 pc[P_DIM];   // {Ar*DT, Ai*DT/2pi}

    const int tid  = threadIdx.x;
    const int lane = tid & 63;
    const int w    = tid >> 6;        // wave 0..3
    const int wm   = w & 1;           // m-half of wave
    const int wn   = w >> 1;          // n-half of wave
    const int m0   = blockIdx.y * BM;
    const int nb   = blockIdx.x * BN;
    const int lb   = blockIdx.x * (BN / 2);   // l-range of this block

    // per-p constants (once per block)
    #pragma unroll
    for (int i = 0; i < 4; ++i) {
        int p = i * 256 + tid;
        float2 a = ((const float2*)Ag)[p];
        pc[p] = make_float2(a.x * DT, a.y * DT * 0.15915494309189535f);
    }
    __syncthreads();

    f32x4 acc[4][4];
    #pragma unroll
    for (int mt = 0; mt < 4; ++mt)
        #pragma unroll
        for (int nt = 0; nt < 4; ++nt)
            acc[mt][nt] = (f32x4){0.f, 0.f, 0.f, 0.f};

    // V-gen mapping: thread -> l = tid>>2 (0..63), q-pairs q = (tid&3)+4i (p = 2q,2q+1)
    const int lv   = tid >> 2;
    const float fl = (float)(lb + lv);
    const int n0   = 2 * lv;
    const int qb   = tid & 3;

    for (int kk = 0; kk < 32; ++kk) {
        const int k0 = kk * BK;
        if (kk) __syncthreads();      // prior MFMA reads done

        // ---- stage A tile via async global->LDS (16B/lane, XOR-permuted k-groups) ----
        {
            const _Float16* gw = W2 + (size_t)(m0 + (w << 5)) * 2048 + k0;
            const int goff = (lane >> 3) * 2048 + (((lane & 7) ^ (lane >> 3)) << 3);
            _Float16* lbase = As + (w << 5) * 64;
            #pragma unroll
            for (int r = 0; r < 4; ++r) {
                __builtin_amdgcn_global_load_lds(GPTR(gw + r * 8 * 2048 + goff),
                                                 LPTR(lbase + r * 8 * 64), 16, 0, 0);
            }
        }

        // ---- generate V_hat tile into Bs (n-major, swizzled) ----
        #pragma unroll
        for (int i = 0; i < 4; ++i) {
            int q = qb + (i << 2);                       // 0..15, p = 2q,2q+1
            float4 pcv = *(const float4*)&pc[(k0 >> 1) + 2 * q];
            float mg0 = __expf(pcv.x * fl);
            float x0 = pcv.y * fl; x0 -= rintf(x0);
            float s0, c0; __sincosf(x0 * TWOPI, &s0, &c0);
            float vr0 = mg0 * c0, vi0 = mg0 * s0;
            float mg1 = __expf(pcv.z * fl);
            float x1 = pcv.w * fl; x1 -= rintf(x1);
            float s1, c1; __sincosf(x1 * TWOPI, &s1, &c1);
            float vr1 = mg1 * c1, vi1 = mg1 * s1;

            H2U a0, a1, b0, b1;
            a0.h = __float22half2_rn(make_float2(vr0, -vi0));   // row 2l: k=4q..4q+1
            a1.h = __float22half2_rn(make_float2(vr1, -vi1));   //         k=4q+2..4q+3
            b0.h = __float22half2_rn(make_float2(vi0, vr0));    // row 2l+1
            b1.h = __float22half2_rn(make_float2(vi1, vr1));
            int grp = q >> 1, sub = (q & 1) << 2;
            int e0 = n0 * 64 + ((grp ^ (n0 & 7)) << 3) + sub;
            int e1 = (n0 + 1) * 64 + ((grp ^ ((n0 + 1) & 7)) << 3) + sub;
            *(uint2*)(Bs + e0) = make_uint2(a0.u, a1.u);
            *(uint2*)(Bs + e1) = make_uint2(b0.u, b1.u);
        }
        __syncthreads();   // A-DMA drained (vmcnt) + V writes visible

        // ---- MFMA: 2 k-halves of 32, 4x4 tiles of 16x16 per wave ----
        #pragma unroll
        for (int ks = 0; ks < 2; ++ks) {
            f16x8 af[4], bf[4];
            const int g = ks * 4 + (lane >> 4);
            #pragma unroll
            for (int t = 0; t < 4; ++t) {
                int m = wm * 64 + t * 16 + (lane & 15);
                af[t] = *(const f16x8*)(As + m * 64 + ((g ^ (m & 7)) << 3));
                int n = wn * 64 + t * 16 + (lane & 15);
                bf[t] = *(const f16x8*)(Bs + n * 64 + ((g ^ (n & 7)) << 3));
            }
            #pragma unroll
            for (int mt = 0; mt < 4; ++mt)
                #pragma unroll
                for (int nt = 0; nt < 4; ++nt)
                    acc[mt][nt] = __builtin_amdgcn_mfma_f32_16x16x32_f16(
                        af[mt], bf[nt], acc[mt][nt], 0, 0, 0);
        }
    }

    // ---- epilogue: D row = (lane>>4)*4 + r, col = lane&15; unscale ----
    #pragma unroll
    for (int mt = 0; mt < 4; ++mt) {
        #pragma unroll
        for (int nt = 0; nt < 4; ++nt) {
            int h = m0 + wm * 64 + mt * 16 + ((lane >> 4) << 2);
            int n = nb + wn * 64 + nt * 16 + (lane & 15);
            #pragma unroll
            for (int r = 0; r < 4; ++r)
                out[(size_t)(h + r) * 32768 + n] = acc[mt][nt][r] * INV_WSCALE;
        }
    }
}

extern "C" void kernel_launch(void* const* d_in, const int* in_sizes, int n_in,
                              void* d_out, int out_size, void* d_ws, size_t ws_size,
                              hipStream_t stream) {
    const float* A = (const float*)d_in[0];   // (P, 2)
    const float* B = (const float*)d_in[1];   // (P, H, 2)
    const float* C = (const float*)d_in[2];   // (H, P, 2)
    float* out = (float*)d_out;               // (H, L, 2)
    __half* W2 = (__half*)d_ws;               // (256, 2048) fp16, 1 MB

    prep_kernel<<<dim3(1024), dim3(256), 0, stream>>>(A, B, C, W2);
    vand_mfma_kernel<<<dim3(L_DIM * 2 / BN, H_DIM / BM), dim3(NTHREADS), 0, stream>>>(
        A, (const _Float16*)W2, out);
}

// Round 3
// 111.792 us; speedup vs baseline: 4.4655x; 1.0336x over previous
//
#include <hip/hip_runtime.h>
#include <hip/hip_fp16.h>

#define P_DIM 1024
#define H_DIM 256
#define L_DIM 16384
#define DT 0.001f
#define TWOPI 6.283185307179586f
#define INV2PI 0.15915494309189535f
#define WSCALE 4096.0f
#define INV_WSCALE (1.0f / 4096.0f)
#define BM 128
#define BN 128
#define BK 64
#define NT 256

typedef _Float16 f16x8 __attribute__((ext_vector_type(8)));
typedef float f32x4 __attribute__((ext_vector_type(4)));

#define GPTR(p) (const __attribute__((address_space(1))) unsigned*)(p)
#define LPTR(p) (__attribute__((address_space(3))) unsigned*)(p)

union H2U { __half2 h; unsigned u; };

__device__ __forceinline__ float2 cmulf(float2 a, float2 b) {
    return make_float2(a.x * b.x - a.y * b.y, a.x * b.y + a.y * b.x);
}

// ---------- prep: W2[h][p] = C[h,p]*scale(p)*B[p,h] * 4096, fp16 pair ----------
// Tile 32h x 64p, all loads/stores coalesced; B transposed through LDS.
__global__ __launch_bounds__(256)
void prep_kernel(const float* __restrict__ Ag, const float* __restrict__ Bg,
                 const float* __restrict__ Cg, __half* __restrict__ W2) {
    __shared__ float2 Bt[64][33];   // [p][h] tile, padded
    __shared__ float2 sc[64];
    const int t  = threadIdx.x;
    const int p0 = (blockIdx.x & 15) << 6;   // 16 p-blocks of 64
    const int h0 = (blockIdx.x >> 4) << 5;   // 8 h-blocks of 32

    if (t < 64) {
        float2 a = ((const float2*)Ag)[p0 + t];
        float er = __expf(a.x * DT);
        float s, c; __sincosf(a.y * DT, &s, &c);
        float nr = er * c - 1.f, ni = er * s;
        float inv = 1.f / (a.x * a.x + a.y * a.y);
        sc[t] = make_float2((nr * a.x + ni * a.y) * inv, (ni * a.x - nr * a.y) * inv);
    }
    #pragma unroll
    for (int i = 0; i < 8; ++i) {           // B: (p,h) layout, h fastest -> coalesced
        int idx = i * 256 + t, p = idx >> 5, h = idx & 31;
        Bt[p][h] = ((const float2*)Bg)[(size_t)(p0 + p) * H_DIM + h0 + h];
    }
    __syncthreads();
    #pragma unroll
    for (int i = 0; i < 8; ++i) {           // C: (h,p) layout, p fastest -> coalesced
        int idx = i * 256 + t, h = idx >> 6, p = idx & 63;
        float2 cc = ((const float2*)Cg)[(size_t)(h0 + h) * P_DIM + p0 + p];
        float2 s2 = sc[p], b = Bt[p][h0 ? h : h];   // Bt[p][h]
        float2 tv = cmulf(cc, s2);
        float wr = (tv.x * b.x - tv.y * b.y) * WSCALE;
        float wi = (tv.x * b.y + tv.y * b.x) * WSCALE;
        ((__half2*)W2)[(size_t)(h0 + h) * P_DIM + p0 + p] =
            __float22half2_rn(make_float2(wr, wi));
    }
}

// ---------- main: fused GEMM + V-gen, double-buffered, 1 barrier/chunk ----------
__global__ __launch_bounds__(NT, 2)
void vand_mfma_kernel(const float* __restrict__ Ag,
                      const _Float16* __restrict__ W2,
                      float* __restrict__ out) {
    __shared__ __attribute__((aligned(16))) _Float16 As[2][BM * BK];  // 2x16KB
    __shared__ __attribute__((aligned(16))) _Float16 Bs[2][BN * BK];  // 2x16KB

    const int tid  = threadIdx.x;
    const int lane = tid & 63;
    const int w    = tid >> 6;
    const int wm   = w & 1, wn = w >> 1;
    const int m0   = blockIdx.y * BM;
    const int nb   = blockIdx.x * BN;
    const int lb   = blockIdx.x * (BN / 2);

    const float2* Ag2 = (const float2*)Ag;

    f32x4 acc[4][4];
    #pragma unroll
    for (int mt = 0; mt < 4; ++mt)
        #pragma unroll
        for (int nt = 0; nt < 4; ++nt)
            acc[mt][nt] = (f32x4){0.f, 0.f, 0.f, 0.f};

    // V-gen mapping: thread -> p-pair q, l = lb + llq .. +3 (recurrence over l)
    const int q    = tid & 15;
    const int llq  = (tid >> 4) << 2;
    const float l0f = (float)(lb + llq);
    const int grp  = q >> 1, sub = (q & 1) << 2;

    // DMA mapping (per wave: 32 rows of A)
    const int goff = (lane >> 3) * 2048 + (((lane & 7) ^ (lane >> 3)) << 3);
    const _Float16* gwbase = W2 + (size_t)(m0 + (w << 5)) * 2048;
    const int ldsoff = (w << 5) * 64;

    _Float16* Acur = &As[0][0]; _Float16* Bcur = &Bs[0][0];
    _Float16* Anxt = &As[1][0]; _Float16* Bnxt = &Bs[1][0];

#define DMA_CHUNK(K0, DST)                                                        \
    {                                                                             \
        const _Float16* gw = gwbase + (K0) + goff;                                \
        _Float16* lB = (DST) + ldsoff;                                            \
        _Pragma("unroll")                                                         \
        for (int r = 0; r < 4; ++r)                                               \
            __builtin_amdgcn_global_load_lds(GPTR(gw + r * 8 * 2048),             \
                                             LPTR(lB + r * 8 * 64), 16, 0, 0);    \
    }

#define VGEN_CHUNK(K0, DST)                                                       \
    {                                                                             \
        float2 a0 = Ag2[((K0) >> 1) + 2 * q];                                     \
        float2 a1 = Ag2[((K0) >> 1) + 2 * q + 1];                                 \
        float c0x = a0.x * DT, c0y = a0.y * (DT * INV2PI);                        \
        float c1x = a1.x * DT, c1y = a1.y * (DT * INV2PI);                        \
        float s, c;                                                               \
        float e0 = __expf(c0x); __sincosf(c0y * TWOPI, &s, &c);                   \
        float2 ab0 = make_float2(e0 * c, e0 * s);                                 \
        float e1 = __expf(c1x); __sincosf(c1y * TWOPI, &s, &c);                   \
        float2 ab1 = make_float2(e1 * c, e1 * s);                                 \
        float mg = __expf(c0x * l0f);                                             \
        float x = c0y * l0f; x -= rintf(x); __sincosf(x * TWOPI, &s, &c);         \
        float2 v0 = make_float2(mg * c, mg * s);                                  \
        mg = __expf(c1x * l0f);                                                   \
        x = c1y * l0f; x -= rintf(x); __sincosf(x * TWOPI, &s, &c);               \
        float2 v1 = make_float2(mg * c, mg * s);                                  \
        _Pragma("unroll")                                                         \
        for (int j = 0; j < 4; ++j) {                                             \
            int n0 = 2 * (llq + j);                                               \
            H2U h0u, h1u, h2u, h3u;                                               \
            h0u.h = __float22half2_rn(make_float2(v0.x, -v0.y));                  \
            h1u.h = __float22half2_rn(make_float2(v1.x, -v1.y));                  \
            h2u.h = __float22half2_rn(make_float2(v0.y, v0.x));                   \
            h3u.h = __float22half2_rn(make_float2(v1.y, v1.x));                   \
            int e0i = n0 * 64 + ((grp ^ (n0 & 7)) << 3) + sub;                    \
            int e1i = (n0 + 1) * 64 + ((grp ^ ((n0 + 1) & 7)) << 3) + sub;        \
            *(uint2*)((DST) + e0i) = make_uint2(h0u.u, h1u.u);                    \
            *(uint2*)((DST) + e1i) = make_uint2(h2u.u, h3u.u);                    \
            if (j < 3) { v0 = cmulf(v0, ab0); v1 = cmulf(v1, ab1); }              \
        }                                                                         \
    }

    // prologue: chunk 0
    DMA_CHUNK(0, Acur)
    VGEN_CHUNK(0, Bcur)
    __syncthreads();

    for (int kk = 0; kk < 32; ++kk) {
        if (kk < 31) {
            const int k1 = (kk + 1) * BK;
            DMA_CHUNK(k1, Anxt)
            VGEN_CHUNK(k1, Bnxt)
        }
        #pragma unroll
        for (int ks = 0; ks < 2; ++ks) {
            f16x8 af[4], bf[4];
            const int g = ks * 4 + (lane >> 4);
            #pragma unroll
            for (int t = 0; t < 4; ++t) {
                int m = wm * 64 + t * 16 + (lane & 15);
                af[t] = *(const f16x8*)(Acur + m * 64 + ((g ^ (m & 7)) << 3));
                int n = wn * 64 + t * 16 + (lane & 15);
                bf[t] = *(const f16x8*)(Bcur + n * 64 + ((g ^ (n & 7)) << 3));
            }
            #pragma unroll
            for (int mt = 0; mt < 4; ++mt)
                #pragma unroll
                for (int nt = 0; nt < 4; ++nt)
                    acc[mt][nt] = __builtin_amdgcn_mfma_f32_16x16x32_f16(
                        af[mt], bf[nt], acc[mt][nt], 0, 0, 0);
        }
        __syncthreads();
        _Float16* tA = Acur; Acur = Anxt; Anxt = tA;
        _Float16* tB = Bcur; Bcur = Bnxt; Bnxt = tB;
    }

    // epilogue: C/D layout col=lane&15, row=(lane>>4)*4+r
    #pragma unroll
    for (int mt = 0; mt < 4; ++mt) {
        #pragma unroll
        for (int nt = 0; nt < 4; ++nt) {
            int h = m0 + wm * 64 + mt * 16 + ((lane >> 4) << 2);
            int n = nb + wn * 64 + nt * 16 + (lane & 15);
            #pragma unroll
            for (int r = 0; r < 4; ++r)
                out[(size_t)(h + r) * 32768 + n] = acc[mt][nt][r] * INV_WSCALE;
        }
    }
#undef DMA_CHUNK
#undef VGEN_CHUNK
}

extern "C" void kernel_launch(void* const* d_in, const int* in_sizes, int n_in,
                              void* d_out, int out_size, void* d_ws, size_t ws_size,
                              hipStream_t stream) {
    const float* A = (const float*)d_in[0];   // (P, 2)
    const float* B = (const float*)d_in[1];   // (P, H, 2)
    const float* C = (const float*)d_in[2];   // (H, P, 2)
    float* out = (float*)d_out;               // (H, L, 2)
    __half* W2 = (__half*)d_ws;               // (256, 2048) fp16, 1 MB

    prep_kernel<<<dim3(128), dim3(256), 0, stream>>>(A, B, C, W2);
    vand_mfma_kernel<<<dim3(L_DIM * 2 / BN, H_DIM / BM), dim3(NT), 0, stream>>>(
        A, (const _Float16*)W2, out);
}